// Round 10
// baseline (32.202 us; speedup 1.0000x reference)
//
#include <hip/hip_runtime.h>
#include <math.h>

#define REG_PARAM 0.0002f
#define COS_EPS 1e-8f
#define INV_N (1.0f / 6291456.0f)

// 1-wave (64-thread) blocks. 8192 main blocks fit residency EXACTLY
// (32 waves/CU x 256 CU); 128 mem blocks are same-sized and retire finely.
// No LDS, no __syncthreads in the producer. Two-kernel form retained
// (fusion abandoned: round-6 threadfence=247us, round-7/8 tickets=48/36us).
#define MEM_BLOCKS 128              // blocks [0,128): mem-cosine path
#define MAIN_BLOCKS 8192            // blocks [128,8320): 3 MSE float4-pairs + 1 entropy row
#define TOTAL_BLOCKS (MEM_BLOCKS + MAIN_BLOCKS)
#define MSE_STRIDE 524288           // 8192 blocks * 64 lanes; n4 = 3*MSE_STRIDE exactly

// Workspace float layout (every slot written unconditionally -> no memset):
// [0,8192)            combined main partials: mse_p*INV_N - REG*ent_p
// [8192,8320)         diag partials (mem blocks)
// [8448,8448+128*256) column-sum partials [128][256] (16B-aligned base)
#define WS_MAIN 0
#define WS_DIAG 8192
#define WS_COL  8448

__device__ __forceinline__ float waveReduceSum(float v) {
    #pragma unroll
    for (int off = 32; off > 0; off >>= 1)
        v += __shfl_xor(v, off, 64);
    return v;
}

__global__ void __launch_bounds__(64)
partials_kernel(const float4* __restrict__ out4,
                const float4* __restrict__ gt4,
                const float4* __restrict__ att4,
                const float4* __restrict__ mem4,
                float* __restrict__ ws) {
    const int lane = threadIdx.x;                // 0..63

    if (blockIdx.x >= MEM_BLOCKS) {
        // ---- main: 3 MSE float4-pairs + 1 entropy row, fully unrolled ----
        const int j = blockIdx.x - MEM_BLOCKS;   // 0..8191
        const int base = (j << 6) + lane;
        float4 a0 = out4[base];
        float4 g0 = gt4 [base];
        float4 a1 = out4[base + MSE_STRIDE];
        float4 g1 = gt4 [base + MSE_STRIDE];
        float4 a2 = out4[base + 2 * MSE_STRIDE];
        float4 g2 = gt4 [base + 2 * MSE_STRIDE];
        const float4* __restrict__ rp = att4 + (size_t)j * 500;   // entropy row j
        float4 x0 = rp[lane];
        float4 x1 = rp[lane + 64];
        float4 x2 = rp[lane + 128];
        float4 x3 = rp[lane + 192];
        float4 x4 = rp[lane + 256];
        float4 x5 = rp[lane + 320];
        float4 x6 = rp[lane + 384];
        float4 x7 = rp[(lane + 448 < 500) ? (lane + 448) : 499];  // clamped addr

        float mse_acc = 0.f, d;
        d = g0.x - a0.x; mse_acc += d * d;
        d = g0.y - a0.y; mse_acc += d * d;
        d = g0.z - a0.z; mse_acc += d * d;
        d = g0.w - a0.w; mse_acc += d * d;
        d = g1.x - a1.x; mse_acc += d * d;
        d = g1.y - a1.y; mse_acc += d * d;
        d = g1.z - a1.z; mse_acc += d * d;
        d = g1.w - a1.w; mse_acc += d * d;
        d = g2.x - a2.x; mse_acc += d * d;
        d = g2.y - a2.y; mse_acc += d * d;
        d = g2.z - a2.z; mse_acc += d * d;
        d = g2.w - a2.w; mse_acc += d * d;

        float z = 0.f, tt = 0.f, e;
        e = __expf(x0.x); z += e; tt += x0.x * e;
        e = __expf(x0.y); z += e; tt += x0.y * e;
        e = __expf(x0.z); z += e; tt += x0.z * e;
        e = __expf(x0.w); z += e; tt += x0.w * e;
        e = __expf(x1.x); z += e; tt += x1.x * e;
        e = __expf(x1.y); z += e; tt += x1.y * e;
        e = __expf(x1.z); z += e; tt += x1.z * e;
        e = __expf(x1.w); z += e; tt += x1.w * e;
        e = __expf(x2.x); z += e; tt += x2.x * e;
        e = __expf(x2.y); z += e; tt += x2.y * e;
        e = __expf(x2.z); z += e; tt += x2.z * e;
        e = __expf(x2.w); z += e; tt += x2.w * e;
        e = __expf(x3.x); z += e; tt += x3.x * e;
        e = __expf(x3.y); z += e; tt += x3.y * e;
        e = __expf(x3.z); z += e; tt += x3.z * e;
        e = __expf(x3.w); z += e; tt += x3.w * e;
        e = __expf(x4.x); z += e; tt += x4.x * e;
        e = __expf(x4.y); z += e; tt += x4.y * e;
        e = __expf(x4.z); z += e; tt += x4.z * e;
        e = __expf(x4.w); z += e; tt += x4.w * e;
        e = __expf(x5.x); z += e; tt += x5.x * e;
        e = __expf(x5.y); z += e; tt += x5.y * e;
        e = __expf(x5.z); z += e; tt += x5.z * e;
        e = __expf(x5.w); z += e; tt += x5.w * e;
        e = __expf(x6.x); z += e; tt += x6.x * e;
        e = __expf(x6.y); z += e; tt += x6.y * e;
        e = __expf(x6.z); z += e; tt += x6.z * e;
        e = __expf(x6.w); z += e; tt += x6.w * e;
        if (lane + 448 < 500) {
            e = __expf(x7.x); z += e; tt += x7.x * e;
            e = __expf(x7.y); z += e; tt += x7.y * e;
            e = __expf(x7.z); z += e; tt += x7.z * e;
            e = __expf(x7.w); z += e; tt += x7.w * e;
        }
        z = waveReduceSum(z);
        tt = waveReduceSum(tt);
        float ent = tt / z - __logf(z);          // sum_j p*logp for this row
        mse_acc = waveReduceSum(mse_acc);

        if (lane == 0)
            ws[WS_MAIN + j] = mse_acc * INV_N - REG_PARAM * ent;
    } else {
        // ---- mem: 15-16 rows per 1-wave block; per-lane column accumulators ----
        const int b = blockIdx.x;                // 0..127
        float c0 = 0.f, c1 = 0.f, c2 = 0.f, c3 = 0.f, dacc = 0.f;
        for (int r = b; r < 2000; r += MEM_BLOCKS) {
            float4 v = mem4[(size_t)r * 64 + lane];   // cols 4*lane..4*lane+3
            float ss = v.x * v.x + v.y * v.y + v.z * v.z + v.w * v.w;
            ss = waveReduceSum(ss);
            float inv = 1.f / fmaxf(sqrtf(ss), COS_EPS);
            c0 += v.x * inv; c1 += v.y * inv; c2 += v.z * inv; c3 += v.w * inv;
            if (lane == 0) dacc += ss * inv * inv;    // gram diagonal (==1 normally)
        }
        ((float4*)(ws + WS_COL))[(b << 6) + lane] = make_float4(c0, c1, c2, c3);
        if (lane == 0) ws[WS_DIAG + b] = dacc;
    }
}

// 1024-thread single-block finalize: 164KB of partials, one latency round.
__global__ void finalize_kernel(const float* __restrict__ ws, float* __restrict__ out) {
    __shared__ float shc[1024];
    __shared__ float shr[16];
    const int t = threadIdx.x;
    const int wid = t >> 6, lane = t & 63;

    float v = 0.f;
    #pragma unroll
    for (int k = 0; k < 8; ++k) v += ws[WS_MAIN + t + (k << 10)];

    const int c = t & 255, s0 = t >> 8;          // 4 threads per column
    float colp = 0.f;
    #pragma unroll
    for (int k = 0; k < 32; ++k)
        colp += ws[WS_COL + ((s0 + (k << 2)) << 8) + c];

    float dv = (t < 128) ? ws[WS_DIAG + t] : 0.f;

    shc[t] = colp;
    __syncthreads();
    float S = 0.f;
    if (t < 256) S = shc[t] + shc[t + 256] + shc[t + 512] + shc[t + 768];

    float r0 = waveReduceSum(v);
    float r1 = waveReduceSum(S * S);
    float r2 = waveReduceSum(dv);
    __syncthreads();
    if (lane == 0) shr[wid] = r0;
    __syncthreads();
    float mainsum = 0.f;
    if (t == 0) {
        #pragma unroll
        for (int k = 0; k < 16; ++k) mainsum += shr[k];
    }
    __syncthreads();
    if (lane == 0) shr[wid] = r1;
    __syncthreads();
    float ssum = 0.f;
    if (t == 0) {
        #pragma unroll
        for (int k = 0; k < 16; ++k) ssum += shr[k];
    }
    __syncthreads();
    if (lane == 0) shr[wid] = r2;
    __syncthreads();
    if (t == 0) {
        float diag = 0.f;
        #pragma unroll
        for (int k = 0; k < 16; ++k) diag += shr[k];
        out[0] = mainsum + 0.5f * (ssum - diag);
    }
}

extern "C" void kernel_launch(void* const* d_in, const int* in_sizes, int n_in,
                              void* d_out, int out_size, void* d_ws, size_t ws_size,
                              hipStream_t stream) {
    const float* out_img = (const float*)d_in[0];   // (32,3,256,256)
    const float* gt      = (const float*)d_in[1];   // (32,3,256,256)
    const float* att     = (const float*)d_in[2];   // (8192,2000)
    const float* mem     = (const float*)d_in[3];   // (2000,256)
    float* ws = (float*)d_ws;
    float* out = (float*)d_out;

    partials_kernel<<<TOTAL_BLOCKS, 64, 0, stream>>>(
        (const float4*)out_img, (const float4*)gt,
        (const float4*)att, (const float4*)mem, ws);
    finalize_kernel<<<1, 1024, 0, stream>>>(ws, out);
}

// Round 11
// 30.281 us; speedup vs baseline: 1.0634x; 1.0634x over previous
//
#include <hip/hip_runtime.h>
#include <math.h>

#define REG_PARAM 0.0002f
#define COS_EPS 1e-8f
#define INV_N (1.0f / 6291456.0f)

#define MEM_BLOCKS 32               // blocks [0,32): mem-cosine path (front of grid)
#define MAIN_BLOCKS 2048            // blocks [32,2080): MSE + entropy fused
#define TOTAL_BLOCKS (MEM_BLOCKS + MAIN_BLOCKS)
#define MSE_STRIDE (MAIN_BLOCKS * 256)   // 524288 float4s; n4 = 3*MSE_STRIDE exactly

// Round-11 idea: att rows half-staged via global_load_lds (LDS-dest loads
// don't occupy VGPRs -> more bytes in flight per CU; the r4-r10 plateau was
// outstanding-capacity bound at ~224KB/CU by the VGPR file).
// Two-kernel form retained (fusion measured worse: r6=247us, r7=48, r8=36).
//
// Workspace float layout (every slot written unconditionally -> no memset):
// [0,2048)            combined main partials: mse_p*INV_N - REG*ent_p
// [2048,2080)         diag partials (mem blocks)
// [2304,2304+32*256)  column-sum partials [32][256]
#define WS_MAIN 0
#define WS_DIAG 2048
#define WS_COL  2304

#define GLOBAL_AS __attribute__((address_space(1)))
#define LDS_AS    __attribute__((address_space(3)))

#define CONSUME4(v) do { float _e; \
    _e = __expf((v).x); z += _e; tt += (v).x * _e; \
    _e = __expf((v).y); z += _e; tt += (v).y * _e; \
    _e = __expf((v).z); z += _e; tt += (v).z * _e; \
    _e = __expf((v).w); z += _e; tt += (v).w * _e; } while (0)

__device__ __forceinline__ float waveReduceSum(float v) {
    #pragma unroll
    for (int off = 32; off > 0; off >>= 1)
        v += __shfl_xor(v, off, 64);
    return v;
}

__global__ void __launch_bounds__(256, 8)
partials_kernel(const float4* __restrict__ out4,
                const float4* __restrict__ gt4,
                const float4* __restrict__ att4,
                const float4* __restrict__ mem4,
                float* __restrict__ ws) {
    // 16 KB shared: main path = 4 rows x 256 float4 staging; mem path = first
    // 1028 floats as reduction scratch.
    __shared__ __align__(16) float smem[4096];
    const int t = threadIdx.x;
    const int wid = t >> 6, lane = t & 63;

    if (blockIdx.x >= MEM_BLOCKS) {
        // ---- main: 3 MSE float4-pairs + 1 entropy row per wave ----
        const int b = blockIdx.x - MEM_BLOCKS;       // 0..2047
        const int base = (b << 8) + t;
        // (1) MSE register loads (oldest in vmcnt queue)
        float4 a0 = out4[base];
        float4 g0 = gt4 [base];
        float4 a1 = out4[base + MSE_STRIDE];
        float4 g1 = gt4 [base + MSE_STRIDE];
        float4 a2 = out4[base + 2 * MSE_STRIDE];
        float4 g2 = gt4 [base + 2 * MSE_STRIDE];

        // (2) stage first 250 float4s of the row into LDS (no VGPR cost)
        const int row = (b << 2) + wid;              // rows 0..8191 exactly once
        const float4* __restrict__ rp = att4 + (size_t)row * 500;
        float4* stagef4 = (float4*)smem;             // [4][256] float4
        #pragma unroll
        for (int k = 0; k < 4; ++k) {
            int gi = k * 64 + lane;                  // per-lane global src
            if (gi > 249) gi = 249;                  // clamp (dup into pad)
            __builtin_amdgcn_global_load_lds(
                (const GLOBAL_AS void*)(rp + gi),
                (LDS_AS void*)(stagef4 + (wid << 8) + (k << 6)),  // wave-uniform base
                16, 0, 0);
        }

        // (3) second 250 float4s into registers
        float4 x4 = rp[250 + lane];
        float4 x5 = rp[314 + lane];
        float4 x6 = rp[378 + lane];
        float4 x7 = rp[(442 + lane < 500) ? (442 + lane) : 499];

        // consume MSE (needs only the 6 oldest loads)
        float mse_acc = 0.f, d;
        d = g0.x - a0.x; mse_acc += d * d;
        d = g0.y - a0.y; mse_acc += d * d;
        d = g0.z - a0.z; mse_acc += d * d;
        d = g0.w - a0.w; mse_acc += d * d;
        d = g1.x - a1.x; mse_acc += d * d;
        d = g1.y - a1.y; mse_acc += d * d;
        d = g1.z - a1.z; mse_acc += d * d;
        d = g1.w - a1.w; mse_acc += d * d;
        d = g2.x - a2.x; mse_acc += d * d;
        d = g2.y - a2.y; mse_acc += d * d;
        d = g2.z - a2.z; mse_acc += d * d;
        d = g2.w - a2.w; mse_acc += d * d;

        // consume register half of the entropy row
        float z = 0.f, tt = 0.f;
        CONSUME4(x4);
        CONSUME4(x5);
        CONSUME4(x6);
        if (lane < 58) CONSUME4(x7);

        // staging complete (x7 consumption already drained vmcnt, but be explicit;
        // "memory" clobber keeps the ds_reads below from hoisting)
        asm volatile("s_waitcnt vmcnt(0)" ::: "memory");

        // consume LDS half (each wave reads only its own staged row: no barrier)
        float4 y0 = stagef4[(wid << 8) + lane];
        float4 y1 = stagef4[(wid << 8) + 64 + lane];
        float4 y2 = stagef4[(wid << 8) + 128 + lane];
        float4 y3 = stagef4[(wid << 8) + 192 + ((lane < 58) ? lane : 57)];
        CONSUME4(y0);
        CONSUME4(y1);
        CONSUME4(y2);
        if (lane < 58) CONSUME4(y3);

        z = waveReduceSum(z);
        tt = waveReduceSum(tt);
        float ent = tt / z - __logf(z);              // sum_j p*logp for this row
        mse_acc = waveReduceSum(mse_acc);

        // Per-wave partial -> one combined float per block via LDS is avoided:
        // write per-wave into block slot through lane0 of each wave, combined by
        // wave 0 after a barrier would need sync; instead keep r5 scheme:
        __syncthreads();                             // staging region reuse barrier
        if (lane == 0) {
            smem[wid] = mse_acc;
            smem[4 + wid] = ent;
        }
        __syncthreads();
        if (t == 0) {
            ws[WS_MAIN + b] = (smem[0] + smem[1] + smem[2] + smem[3]) * INV_N
                            - REG_PARAM * (smem[4] + smem[5] + smem[6] + smem[7]);
        }
    } else {
        // ---- mem: wave-per-row normalize; per-lane column accumulators ----
        float* sh = smem;                            // [1024]
        float* shd = smem + 1024;                    // [4]
        const int mb = blockIdx.x;                   // 0..31
        const int wglobal = mb * 4 + wid;            // 0..127
        float c0 = 0.f, c1 = 0.f, c2 = 0.f, c3 = 0.f, dacc = 0.f;
        for (int r = wglobal; r < 2000; r += MEM_BLOCKS * 4) {
            float4 v = mem4[(size_t)r * 64 + lane];  // cols 4*lane..4*lane+3
            float ss = v.x * v.x + v.y * v.y + v.z * v.z + v.w * v.w;
            ss = waveReduceSum(ss);
            float inv = 1.f / fmaxf(sqrtf(ss), COS_EPS);
            c0 += v.x * inv; c1 += v.y * inv; c2 += v.z * inv; c3 += v.w * inv;
            if (lane == 0) dacc += ss * inv * inv;   // gram diagonal (==1 normally)
        }
        if (lane == 0) shd[wid] = dacc;
        sh[wid * 256 + lane * 4 + 0] = c0;
        sh[wid * 256 + lane * 4 + 1] = c1;
        sh[wid * 256 + lane * 4 + 2] = c2;
        sh[wid * 256 + lane * 4 + 3] = c3;
        __syncthreads();
        ws[WS_COL + mb * 256 + t] = sh[t] + sh[256 + t] + sh[512 + t] + sh[768 + t];
        if (t == 0) ws[WS_DIAG + mb] = shd[0] + shd[1] + shd[2] + shd[3];
    }
}

// 1024-thread single-block finalize (r9): one latency round over ~41KB.
__global__ void finalize_kernel(const float* __restrict__ ws, float* __restrict__ out) {
    __shared__ float shc[1024];
    __shared__ float shr[16];
    const int t = threadIdx.x;
    const int wid = t >> 6, lane = t & 63;

    float v = ws[WS_MAIN + t] + ws[WS_MAIN + t + 1024];

    const int c = t & 255, s0 = t >> 8;          // 4 threads per column
    float colp = 0.f;
    #pragma unroll
    for (int k = 0; k < 8; ++k)
        colp += ws[WS_COL + ((s0 + (k << 2)) << 8) + c];

    float dv = (t < 32) ? ws[WS_DIAG + t] : 0.f;

    shc[t] = colp;
    __syncthreads();
    float S = 0.f;
    if (t < 256) S = shc[t] + shc[t + 256] + shc[t + 512] + shc[t + 768];

    float r0 = waveReduceSum(v);
    float r1 = waveReduceSum(S * S);
    float r2 = waveReduceSum(dv);
    __syncthreads();
    if (lane == 0) shr[wid] = r0;
    __syncthreads();
    float mainsum = 0.f;
    if (t == 0) {
        #pragma unroll
        for (int k = 0; k < 16; ++k) mainsum += shr[k];
    }
    __syncthreads();
    if (lane == 0) shr[wid] = r1;
    __syncthreads();
    float ssum = 0.f;
    if (t == 0) {
        #pragma unroll
        for (int k = 0; k < 16; ++k) ssum += shr[k];
    }
    __syncthreads();
    if (lane == 0) shr[wid] = r2;
    __syncthreads();
    if (t == 0) {
        float diag = 0.f;
        #pragma unroll
        for (int k = 0; k < 16; ++k) diag += shr[k];
        out[0] = mainsum + 0.5f * (ssum - diag);
    }
}

extern "C" void kernel_launch(void* const* d_in, const int* in_sizes, int n_in,
                              void* d_out, int out_size, void* d_ws, size_t ws_size,
                              hipStream_t stream) {
    const float* out_img = (const float*)d_in[0];   // (32,3,256,256)
    const float* gt      = (const float*)d_in[1];   // (32,3,256,256)
    const float* att     = (const float*)d_in[2];   // (8192,2000)
    const float* mem     = (const float*)d_in[3];   // (2000,256)
    float* ws = (float*)d_ws;
    float* out = (float*)d_out;

    partials_kernel<<<TOTAL_BLOCKS, 256, 0, stream>>>(
        (const float4*)out_img, (const float4*)gt,
        (const float4*)att, (const float4*)mem, ws);
    finalize_kernel<<<1, 1024, 0, stream>>>(ws, out);
}

// Round 12
// 29.336 us; speedup vs baseline: 1.0977x; 1.0322x over previous
//
#include <hip/hip_runtime.h>
#include <math.h>

#define REG_PARAM 0.0002f
#define COS_EPS 1e-8f
#define INV_N (1.0f / 6291456.0f)

#define MEM_BLOCKS 32               // blocks [0,32): mem-cosine path (front of grid)
#define MAIN_BLOCKS 2048            // blocks [32,2080): MSE + entropy fused
#define TOTAL_BLOCKS (MEM_BLOCKS + MAIN_BLOCKS)
#define MSE_STRIDE (MAIN_BLOCKS * 256)   // 524288 float4s; n4 = 3*MSE_STRIDE exactly

// FINAL (round-12): exact round-5 kernel, the measured best (29.08us;
// r9 variant reproduced 29.15). Session evidence:
//  - fusion (threadfence)          247us  [r6: per-block L2 writeback]
//  - fusion (flat ticket atomics)   48us  [r7: 2080 same-addr atomics ~13ns each]
//  - fusion (ticket tree)           36us  [r8: uncached agent ALOAD finalize tail]
//  - 1-wave blocks                  32.2us [r10: dispatch overhead > tail saved]
//  - global_load_lds staging        30.3us [r11: compiler rebalances VGPR, null]
//  - this two-kernel form           29.1us
// Remaining gap to ~19-20us arithmetic floor = fixed 2-node overhead + L3
// eviction by the harness's 268MB inter-replay fills (structure-invariant).
//
// Workspace float layout (every slot written unconditionally -> no memset):
// [0,2048)            combined main partials: mse_p*INV_N - REG*ent_p
// [2048,2080)         diag partials (mem blocks)
// [2304,2304+32*256)  column-sum partials [32][256]
#define WS_MAIN 0
#define WS_DIAG 2048
#define WS_COL  2304

__device__ __forceinline__ float waveReduceSum(float v) {
    #pragma unroll
    for (int off = 32; off > 0; off >>= 1)
        v += __shfl_xor(v, off, 64);
    return v;
}

__device__ __forceinline__ float blockReduceSum(float v, float* sh) {
    v = waveReduceSum(v);
    int wid = threadIdx.x >> 6, lane = threadIdx.x & 63;
    __syncthreads();
    if (lane == 0) sh[wid] = v;
    __syncthreads();
    return sh[0] + sh[1] + sh[2] + sh[3];
}

__global__ void partials_kernel(const float4* __restrict__ out4,
                                const float4* __restrict__ gt4,
                                const float4* __restrict__ att4,
                                const float4* __restrict__ mem4,
                                float* __restrict__ ws) {
    __shared__ float sh[4 * 256];   // mem path uses all 1024; main path uses [0,8)
    __shared__ float shd[4];
    const int t = threadIdx.x;
    const int wid = t >> 6, lane = t & 63;

    if (blockIdx.x >= MEM_BLOCKS) {
        // ---- main: 3 MSE float4-pairs + 1 entropy row per wave, fully unrolled ----
        const int b = blockIdx.x - MEM_BLOCKS;       // 0..2047
        const int base = (b << 8) + t;
        float4 a0 = out4[base];
        float4 g0 = gt4 [base];
        float4 a1 = out4[base + MSE_STRIDE];
        float4 g1 = gt4 [base + MSE_STRIDE];
        float4 a2 = out4[base + 2 * MSE_STRIDE];
        float4 g2 = gt4 [base + 2 * MSE_STRIDE];
        const int row = (b << 2) + wid;              // rows 0..8191 exactly once
        const float4* __restrict__ rp = att4 + (size_t)row * 500;
        float4 x0 = rp[lane];
        float4 x1 = rp[lane + 64];
        float4 x2 = rp[lane + 128];
        float4 x3 = rp[lane + 192];
        float4 x4 = rp[lane + 256];
        float4 x5 = rp[lane + 320];
        float4 x6 = rp[lane + 384];
        float4 x7 = rp[(lane + 448 < 500) ? (lane + 448) : 499];  // clamped addr

        float mse_acc = 0.f, d;
        d = g0.x - a0.x; mse_acc += d * d;
        d = g0.y - a0.y; mse_acc += d * d;
        d = g0.z - a0.z; mse_acc += d * d;
        d = g0.w - a0.w; mse_acc += d * d;
        d = g1.x - a1.x; mse_acc += d * d;
        d = g1.y - a1.y; mse_acc += d * d;
        d = g1.z - a1.z; mse_acc += d * d;
        d = g1.w - a1.w; mse_acc += d * d;
        d = g2.x - a2.x; mse_acc += d * d;
        d = g2.y - a2.y; mse_acc += d * d;
        d = g2.z - a2.z; mse_acc += d * d;
        d = g2.w - a2.w; mse_acc += d * d;

        float z = 0.f, tt = 0.f, e;
        e = __expf(x0.x); z += e; tt += x0.x * e;
        e = __expf(x0.y); z += e; tt += x0.y * e;
        e = __expf(x0.z); z += e; tt += x0.z * e;
        e = __expf(x0.w); z += e; tt += x0.w * e;
        e = __expf(x1.x); z += e; tt += x1.x * e;
        e = __expf(x1.y); z += e; tt += x1.y * e;
        e = __expf(x1.z); z += e; tt += x1.z * e;
        e = __expf(x1.w); z += e; tt += x1.w * e;
        e = __expf(x2.x); z += e; tt += x2.x * e;
        e = __expf(x2.y); z += e; tt += x2.y * e;
        e = __expf(x2.z); z += e; tt += x2.z * e;
        e = __expf(x2.w); z += e; tt += x2.w * e;
        e = __expf(x3.x); z += e; tt += x3.x * e;
        e = __expf(x3.y); z += e; tt += x3.y * e;
        e = __expf(x3.z); z += e; tt += x3.z * e;
        e = __expf(x3.w); z += e; tt += x3.w * e;
        e = __expf(x4.x); z += e; tt += x4.x * e;
        e = __expf(x4.y); z += e; tt += x4.y * e;
        e = __expf(x4.z); z += e; tt += x4.z * e;
        e = __expf(x4.w); z += e; tt += x4.w * e;
        e = __expf(x5.x); z += e; tt += x5.x * e;
        e = __expf(x5.y); z += e; tt += x5.y * e;
        e = __expf(x5.z); z += e; tt += x5.z * e;
        e = __expf(x5.w); z += e; tt += x5.w * e;
        e = __expf(x6.x); z += e; tt += x6.x * e;
        e = __expf(x6.y); z += e; tt += x6.y * e;
        e = __expf(x6.z); z += e; tt += x6.z * e;
        e = __expf(x6.w); z += e; tt += x6.w * e;
        if (lane + 448 < 500) {
            e = __expf(x7.x); z += e; tt += x7.x * e;
            e = __expf(x7.y); z += e; tt += x7.y * e;
            e = __expf(x7.z); z += e; tt += x7.z * e;
            e = __expf(x7.w); z += e; tt += x7.w * e;
        }
        z = waveReduceSum(z);
        tt = waveReduceSum(tt);
        float ent = tt / z - __logf(z);              // sum_j p*logp for this row

        mse_acc = waveReduceSum(mse_acc);
        if (lane == 0) { sh[wid] = mse_acc; sh[4 + wid] = ent; }
        __syncthreads();
        if (t == 0) {
            ws[WS_MAIN + b] = (sh[0] + sh[1] + sh[2] + sh[3]) * INV_N
                            - REG_PARAM * (sh[4] + sh[5] + sh[6] + sh[7]);
        }
    } else {
        // ---- mem: wave-per-row normalize; per-lane column accumulators ----
        const int mb = blockIdx.x;                           // 0..31
        const int wglobal = mb * 4 + wid;                    // 0..127
        float c0 = 0.f, c1 = 0.f, c2 = 0.f, c3 = 0.f, dacc = 0.f;
        for (int row = wglobal; row < 2000; row += MEM_BLOCKS * 4) {
            float4 v = mem4[(size_t)row * 64 + lane];        // cols 4*lane..4*lane+3
            float ss = v.x * v.x + v.y * v.y + v.z * v.z + v.w * v.w;
            ss = waveReduceSum(ss);
            float inv = 1.f / fmaxf(sqrtf(ss), COS_EPS);
            c0 += v.x * inv; c1 += v.y * inv; c2 += v.z * inv; c3 += v.w * inv;
            if (lane == 0) dacc += ss * inv * inv;           // gram diagonal (==1 normally)
        }
        if (lane == 0) shd[wid] = dacc;
        sh[wid * 256 + lane * 4 + 0] = c0;
        sh[wid * 256 + lane * 4 + 1] = c1;
        sh[wid * 256 + lane * 4 + 2] = c2;
        sh[wid * 256 + lane * 4 + 3] = c3;
        __syncthreads();
        ws[WS_COL + mb * 256 + t] = sh[t] + sh[256 + t] + sh[512 + t] + sh[768 + t];
        if (t == 0) ws[WS_DIAG + mb] = shd[0] + shd[1] + shd[2] + shd[3];
    }
}

// Single-block reduction of all partials -> scalar loss.
__global__ void finalize_kernel(const float* __restrict__ ws, float* __restrict__ out) {
    __shared__ float sh[4];
    const int t = threadIdx.x;

    float v = 0.f;
    #pragma unroll
    for (int k = 0; k < 8; ++k) v += ws[WS_MAIN + t + (k << 8)];
    float mainsum = blockReduceSum(v, sh);

    float S = 0.f;
    #pragma unroll
    for (int mb = 0; mb < 32; ++mb) S += ws[WS_COL + (mb << 8) + t];
    float ssum = blockReduceSum(S * S, sh);      // ||S||^2

    float dv = (t < 32) ? ws[WS_DIAG + t] : 0.f;
    float diag = blockReduceSum(dv, sh);

    if (t == 0) {
        out[0] = mainsum + 0.5f * (ssum - diag);
    }
}

extern "C" void kernel_launch(void* const* d_in, const int* in_sizes, int n_in,
                              void* d_out, int out_size, void* d_ws, size_t ws_size,
                              hipStream_t stream) {
    const float* out_img = (const float*)d_in[0];   // (32,3,256,256)
    const float* gt      = (const float*)d_in[1];   // (32,3,256,256)
    const float* att     = (const float*)d_in[2];   // (8192,2000)
    const float* mem     = (const float*)d_in[3];   // (2000,256)
    float* ws = (float*)d_ws;
    float* out = (float*)d_out;

    partials_kernel<<<TOTAL_BLOCKS, 256, 0, stream>>>(
        (const float4*)out_img, (const float4*)gt,
        (const float4*)att, (const float4*)mem, ws);
    finalize_kernel<<<1, 256, 0, stream>>>(ws, out);
}